// Round 3
// baseline (3160.333 us; speedup 1.0000x reference)
//
#include <hip/hip_runtime.h>

#define B_   2048   // batch
#define H_   512    // hidden
#define I_   128    // input size
#define G4   2048   // 4*H
#define SEQ  100
#define DEC  29
#define OUT_ 128
#define TEAM 16     // blocks per row-slab team

typedef __attribute__((ext_vector_type(8))) short bf16x8;
typedef __attribute__((ext_vector_type(4))) float f32x4;
typedef __attribute__((address_space(3))) unsigned int       lds_u32;
typedef __attribute__((address_space(1))) const unsigned int glb_u32c;

__device__ inline unsigned short f2bf(float f) {
    union { float f; unsigned int u; } v; v.f = f;
    unsigned int u = v.u + 0x7fffu + ((v.u >> 16) & 1u);
    return (unsigned short)(u >> 16);
}
__device__ inline float sigm(float x)  { return 1.f / (1.f + __expf(-x)); }
__device__ inline float tanh_(float x) { return 2.f / (1.f + __expf(-2.f * x)) - 1.f; }

__device__ inline void gload16(const unsigned short* g, unsigned short* l) {
    __builtin_amdgcn_global_load_lds((glb_u32c*)g, (lds_u32*)l, 16, 0, 0);
}

// Persistent encoder+decoder+projection kernel.
// Grid 256 blocks x 512 thr. Block tile: M=128 batch rows x 32 hidden cols
// (x 4 gates = 128 gate-cols). rg = blockIdx&15 (row slab), cg = blockIdx>>4.
// Team = the 16 blocks sharing a row slab; per-step atomic barrier per team.
// LDS 64 KB: double-buffered {A 16KB | B 16KB} chunk pair (k-chunk = 64).
// c-state and biases live in registers for the whole recurrence.
__global__ __launch_bounds__(512, 2) void persist(
    const unsigned short* __restrict__ h0b,   // [B_,H_] bf16 initial h (zeros)
    const unsigned short* __restrict__ xbf,   // [SEQ,B_,I_] bf16 inputs
    const unsigned short* __restrict__ Wce,   // [G4,640] enc weights (Whh|Wih)
    const unsigned short* __restrict__ Wd,    // [G4,512] dec combined weights
    const unsigned short* __restrict__ Wl,    // [OUT_,512] output proj
    const float* __restrict__ be, const float* __restrict__ bd,
    const float* __restrict__ blin,
    const float* __restrict__ c_enc0, const float* __restrict__ c_dec0,
    unsigned short* __restrict__ hp0, unsigned short* __restrict__ hp1,
    unsigned short* __restrict__ hs,          // [30,B_,H_] bf16
    float* __restrict__ out_y,                // [30,B_,OUT_]
    float* __restrict__ out_hEnc, float* __restrict__ out_cEnc,
    float* __restrict__ out_hDec, float* __restrict__ out_cDec,
    unsigned int* __restrict__ bar)           // [16][64] uints (cnt @0, gen @16)
{
    __shared__ unsigned short smem[32768];    // 64 KB = 2 x (A 8192 | B 8192 elems)

    const int tid  = threadIdx.x;
    const int b    = blockIdx.x;
    const int rg   = b & 15;                  // row-slab / team id
    const int cgB  = b >> 4;                  // col-group 0..15
    const int m0   = rg * 128;
    const int c0   = cgB * 32;

    const int lane = tid & 63, w = tid >> 6;
    const int quad = lane >> 4, l16 = lane & 15;
    const int w_m  = w >> 1, w_n = w & 1;

    unsigned int* bcnt = bar + rg * 64;
    unsigned int* bgen = bcnt + 16;
    unsigned int  my_gen = 0;

    // ---- staging geometry (same swizzle as verified round-2 kernel) ----
    const int  segl = (lane & 7) ^ ((lane >> 3) & 7);
    const bool isA  = (w < 4);
    const int  wS   = isA ? w : (w - 4);
    const int  sRow = wS * 32 + (lane >> 3);   // stage row 0..127 (this wave's 32)

    // fragment read byte offsets (buf 0); +buf*32768 bytes for buf 1
    int offA[2][2], offB[4][2];
#pragma unroll
    for (int rf = 0; rf < 2; ++rf)
#pragma unroll
        for (int ks = 0; ks < 2; ++ks) {
            const int row = w_m * 32 + rf * 16 + l16;
            const int seg = ks * 4 + quad;
            offA[rf][ks] = row * 128 + ((seg ^ (row & 7)) * 16);
        }
#pragma unroll
    for (int g = 0; g < 4; ++g)
#pragma unroll
        for (int ks = 0; ks < 2; ++ks) {
            const int row = g * 32 + w_n * 16 + l16;
            const int seg = ks * 4 + quad;
            offB[g][ks] = 16384 + row * 128 + ((seg ^ (row & 7)) * 16);
        }

    f32x4 acc[2][4];
    float c_reg[2][4];
    const int col = c0 + w_n * 16 + l16;

    // stage one 64-k chunk into buffer `buf`
    auto stage = [&](const unsigned short* Asrc, const unsigned short* Xsrc,
                     const unsigned short* Wsrc, int Kw, int gs, int cb,
                     int kc, int buf) {
        unsigned short* dst = smem + buf * 16384 + (isA ? 0 : 8192) + wS * 2048;
        if (isA) {
            if (Xsrc && kc >= 8) {   // encoder x-chunks (k 512..639)
                const unsigned short* g0 =
                    Xsrc + (size_t)(m0 + sRow) * I_ + (kc - 8) * 64 + segl * 8;
#pragma unroll
                for (int i = 0; i < 4; ++i)
                    gload16(g0 + (size_t)(i * 8) * I_, dst + i * 512);
            } else {
                const unsigned short* g0 =
                    Asrc + (size_t)(m0 + sRow) * H_ + kc * 64 + segl * 8;
#pragma unroll
                for (int i = 0; i < 4; ++i)
                    gload16(g0 + (size_t)(i * 8) * H_, dst + i * 512);
            }
        } else {
#pragma unroll
            for (int i = 0; i < 4; ++i) {
                const int rowN  = sRow + i * 8;                       // 0..127
                const int rglob = (rowN >> 5) * gs + cb + (rowN & 31);
                gload16(Wsrc + (size_t)rglob * Kw + kc * 64 + segl * 8, dst + i * 512);
            }
        }
    };

    // full K-loop GEMM for this block's tile, double-buffered
    auto gemm = [&](const unsigned short* Asrc, const unsigned short* Xsrc,
                    const unsigned short* Wsrc, int Kw, int gs, int cb) {
#pragma unroll
        for (int rf = 0; rf < 2; ++rf)
#pragma unroll
            for (int g = 0; g < 4; ++g) acc[rf][g] = (f32x4){0.f, 0.f, 0.f, 0.f};
        const int kcN = Kw >> 6;
        stage(Asrc, Xsrc, Wsrc, Kw, gs, cb, 0, 0);
        for (int kc = 0; kc < kcN; ++kc) {
            const int buf = kc & 1;
            __syncthreads();                         // buf's chunk is resident
            if (kc + 1 < kcN)                        // prefetch into other buf
                stage(Asrc, Xsrc, Wsrc, Kw, gs, cb, kc + 1, buf ^ 1);
            const char* sb = (const char*)smem + buf * 32768;
#pragma unroll
            for (int ks = 0; ks < 2; ++ks) {
                bf16x8 a0 = *(const bf16x8*)(sb + offA[0][ks]);
                bf16x8 a1 = *(const bf16x8*)(sb + offA[1][ks]);
#pragma unroll
                for (int g = 0; g < 4; ++g) {
                    bf16x8 bb = *(const bf16x8*)(sb + offB[g][ks]);
                    acc[0][g] = __builtin_amdgcn_mfma_f32_16x16x32_bf16(a0, bb, acc[0][g], 0, 0, 0);
                    acc[1][g] = __builtin_amdgcn_mfma_f32_16x16x32_bf16(a1, bb, acc[1][g], 0, 0, 0);
                }
            }
        }
        __syncthreads();
    };

    // team barrier: release h writes -> arrive -> spin on generation -> acquire
    auto team_barrier = [&]() {
        __syncthreads();                 // all waves' stores issued & drained
        if (tid == 0) {
            __threadfence();             // device-scope release
            unsigned old = __hip_atomic_fetch_add(bcnt, 1u, __ATOMIC_ACQ_REL,
                                                  __HIP_MEMORY_SCOPE_AGENT);
            if (old == TEAM - 1) {
                __hip_atomic_store(bcnt, 0u, __ATOMIC_RELAXED, __HIP_MEMORY_SCOPE_AGENT);
                __hip_atomic_fetch_add(bgen, 1u, __ATOMIC_RELEASE, __HIP_MEMORY_SCOPE_AGENT);
            } else {
                while (__hip_atomic_load(bgen, __ATOMIC_RELAXED,
                                         __HIP_MEMORY_SCOPE_AGENT) <= my_gen)
                    __builtin_amdgcn_s_sleep(1);
            }
            __threadfence();             // device-scope acquire
        }
        my_gen++;
        __syncthreads();
    };

    // ================= encoder: 100 steps =================
    float b0 = be[col], b1 = be[H_ + col], b2 = be[2 * H_ + col], b3 = be[3 * H_ + col];
#pragma unroll
    for (int rf = 0; rf < 2; ++rf)
#pragma unroll
        for (int j = 0; j < 4; ++j) {
            const int row = m0 + w_m * 32 + rf * 16 + quad * 4 + j;
            c_reg[rf][j] = c_enc0[(size_t)row * H_ + col];
        }

    for (int t = 0; t < SEQ; ++t) {
        const unsigned short* src = (t == 0) ? h0b : ((t & 1) ? hp0 : hp1);
        unsigned short*       dst = (t == SEQ - 1) ? hs : ((t & 1) ? hp1 : hp0);
        gemm(src, xbf + (size_t)t * B_ * I_, Wce, 640, H_, c0);
        const bool last = (t == SEQ - 1);
#pragma unroll
        for (int rf = 0; rf < 2; ++rf)
#pragma unroll
            for (int j = 0; j < 4; ++j) {
                const int row = m0 + w_m * 32 + rf * 16 + quad * 4 + j;
                const size_t idx = (size_t)row * H_ + col;
                const float gi = acc[rf][0][j] + b0;
                const float gf = acc[rf][1][j] + b1;
                const float gg = acc[rf][2][j] + b2;
                const float go = acc[rf][3][j] + b3;
                const float ii = sigm(gi), ff = sigm(gf);
                const float g2 = tanh_(gg), oo = sigm(go);
                const float cn = ff * c_reg[rf][j] + ii * g2;
                c_reg[rf][j] = cn;
                const float hn = oo * tanh_(cn);
                dst[idx] = f2bf(hn);
                if (last) { out_hEnc[idx] = hn; out_cEnc[idx] = cn; }
            }
        team_barrier();
    }

    // ================= decoder: 29 steps =================
    b0 = bd[col]; b1 = bd[H_ + col]; b2 = bd[2 * H_ + col]; b3 = bd[3 * H_ + col];
#pragma unroll
    for (int rf = 0; rf < 2; ++rf)
#pragma unroll
        for (int j = 0; j < 4; ++j) {
            const int row = m0 + w_m * 32 + rf * 16 + quad * 4 + j;
            c_reg[rf][j] = c_dec0[(size_t)row * H_ + col];
        }

    for (int s = 0; s < DEC; ++s) {
        unsigned short* dst = hs + (size_t)(s + 1) * B_ * H_;
        gemm(hs + (size_t)s * B_ * H_, nullptr, Wd, 512, H_, c0);
        const bool last = (s == DEC - 1);
#pragma unroll
        for (int rf = 0; rf < 2; ++rf)
#pragma unroll
            for (int j = 0; j < 4; ++j) {
                const int row = m0 + w_m * 32 + rf * 16 + quad * 4 + j;
                const size_t idx = (size_t)row * H_ + col;
                const float gi = acc[rf][0][j] + b0;
                const float gf = acc[rf][1][j] + b1;
                const float gg = acc[rf][2][j] + b2;
                const float go = acc[rf][3][j] + b3;
                const float ii = sigm(gi), ff = sigm(gf);
                const float g2 = tanh_(gg), oo = sigm(go);
                const float cn = ff * c_reg[rf][j] + ii * g2;
                c_reg[rf][j] = cn;
                const float hn = oo * tanh_(cn);
                dst[idx] = f2bf(hn);
                if (last) { out_hDec[idx] = hn; out_cDec[idx] = cn; }
            }
        team_barrier();
    }

    // ================= output projection: y[s] = hs[s] @ Wl^T + blin ========
    // Block cgB handles steps s = cgB, cgB+16 for its team's 128 rows.
    for (int s = cgB; s < DEC + 1; s += 16) {
        gemm(hs + (size_t)s * B_ * H_, nullptr, Wl, 512, 32, 0);
#pragma unroll
        for (int g = 0; g < 4; ++g) {
            const int ocol = g * 32 + w_n * 16 + l16;
            const float bb = blin[ocol];
#pragma unroll
            for (int rf = 0; rf < 2; ++rf)
#pragma unroll
                for (int j = 0; j < 4; ++j) {
                    const int row = m0 + w_m * 32 + rf * 16 + quad * 4 + j;
                    out_y[(size_t)s * B_ * OUT_ + (size_t)row * OUT_ + ocol] =
                        acc[rf][g][j] + bb;
                }
        }
    }
}

// Weight prep: Wce[r][k] = k<512 ? Whh_e[r][k] : Wih_e[r][k-512];
// Wd = bf16(Wih_d + Whh_d); Wl = bf16(W_lin); biases combined.
__global__ void prep(const float* __restrict__ whh_e, const float* __restrict__ wih_e,
                     const float* __restrict__ wih_d, const float* __restrict__ whh_d,
                     const float* __restrict__ wlin,
                     const float* __restrict__ bie, const float* __restrict__ bhe,
                     const float* __restrict__ bid, const float* __restrict__ bhd,
                     unsigned short* __restrict__ Wce, unsigned short* __restrict__ Wd,
                     unsigned short* __restrict__ Wl,
                     float* __restrict__ be, float* __restrict__ bd)
{
    const int i = blockIdx.x * blockDim.x + threadIdx.x;
    if (i < G4 * 640) {
        const int r = i / 640, k = i % 640;
        Wce[i] = f2bf(k < H_ ? whh_e[r * H_ + k] : wih_e[r * I_ + (k - H_)]);
    }
    if (i < G4 * H_)   Wd[i] = f2bf(wih_d[i] + whh_d[i]);
    if (i < OUT_ * H_) Wl[i] = f2bf(wlin[i]);
    if (i < G4) { be[i] = bie[i] + bhe[i]; bd[i] = bid[i] + bhd[i]; }
}

__global__ void xconv(const float* __restrict__ x, unsigned short* __restrict__ xb, int n4)
{
    const int i = blockIdx.x * blockDim.x + threadIdx.x;
    if (i < n4) {
        const float4 f = *(const float4*)(x + (size_t)i * 4);
        ushort4 o;
        o.x = f2bf(f.x); o.y = f2bf(f.y); o.z = f2bf(f.z); o.w = f2bf(f.w);
        *(ushort4*)(xb + (size_t)i * 4) = o;
    }
}

__global__ void inith(const float* __restrict__ h0, unsigned short* __restrict__ hb)
{
    const int i = blockIdx.x * blockDim.x + threadIdx.x;
    if (i < B_ * H_) hb[i] = f2bf(h0[i]);
}

extern "C" void kernel_launch(void* const* d_in, const int* in_sizes, int n_in,
                              void* d_out, int out_size, void* d_ws, size_t ws_size,
                              hipStream_t stream) {
    (void)in_sizes; (void)n_in; (void)out_size; (void)ws_size;
    const float* input  = (const float*)d_in[0];
    const float* h_enc0 = (const float*)d_in[1];
    // d_in[2] hidden_decoder is unused by the reference
    const float* c_enc0 = (const float*)d_in[3];
    const float* c_dec0 = (const float*)d_in[4];
    const float* Wih_e  = (const float*)d_in[5];
    const float* Whh_e  = (const float*)d_in[6];
    const float* bih_e  = (const float*)d_in[7];
    const float* bhh_e  = (const float*)d_in[8];
    const float* Wih_d  = (const float*)d_in[9];
    const float* Whh_d  = (const float*)d_in[10];
    const float* bih_d  = (const float*)d_in[11];
    const float* bhh_d  = (const float*)d_in[12];
    const float* Wlin   = (const float*)d_in[13];
    const float* blin   = (const float*)d_in[14];
    float* out = (float*)d_out;

    char* ws = (char*)d_ws;
    size_t off = 0;
    auto alloc = [&](size_t bytes) -> void* {
        void* p = ws + off;
        off = (off + bytes + 255) & ~(size_t)255;
        return p;
    };
    unsigned short* Wce = (unsigned short*)alloc((size_t)G4 * 640 * 2);
    unsigned short* Wd  = (unsigned short*)alloc((size_t)G4 * H_ * 2);
    unsigned short* Wl  = (unsigned short*)alloc((size_t)OUT_ * H_ * 2);
    float* be = (float*)alloc((size_t)G4 * 4);
    float* bd = (float*)alloc((size_t)G4 * 4);
    unsigned short* h0b = (unsigned short*)alloc((size_t)B_ * H_ * 2);
    unsigned short* hp0 = (unsigned short*)alloc((size_t)B_ * H_ * 2);
    unsigned short* hp1 = (unsigned short*)alloc((size_t)B_ * H_ * 2);
    unsigned short* xbf = (unsigned short*)alloc((size_t)SEQ * B_ * I_ * 2);
    unsigned short* hs  = (unsigned short*)alloc((size_t)(DEC + 1) * B_ * H_ * 2);
    unsigned int*   bar = (unsigned int*)alloc(16 * 64 * 4);

    float* out_y    = out;                                   // [30, B_, OUT_]
    float* out_hEnc = out + (size_t)(DEC + 1) * B_ * OUT_;
    float* out_hDec = out_hEnc + (size_t)B_ * H_;
    float* out_cEnc = out_hDec + (size_t)B_ * H_;
    float* out_cDec = out_cEnc + (size_t)B_ * H_;

    prep<<<(G4 * 640 + 255) / 256, 256, 0, stream>>>(
        Whh_e, Wih_e, Wih_d, Whh_d, Wlin, bih_e, bhh_e, bih_d, bhh_d,
        Wce, Wd, Wl, be, bd);
    xconv<<<(SEQ * B_ * I_ / 4 + 255) / 256, 256, 0, stream>>>(input, xbf, SEQ * B_ * I_ / 4);
    inith<<<(B_ * H_ + 255) / 256, 256, 0, stream>>>(h_enc0, h0b);
    hipMemsetAsync(bar, 0, 16 * 64 * 4, stream);

    persist<<<256, 512, 0, stream>>>(
        h0b, xbf, Wce, Wd, Wl, be, bd, blin, c_enc0, c_dec0,
        hp0, hp1, hs, out_y, out_hEnc, out_cEnc, out_hDec, out_cDec, bar);
}

// Round 4
// 1410.857 us; speedup vs baseline: 2.2400x; 2.2400x over previous
//
#include <hip/hip_runtime.h>

#define B_   2048   // batch
#define H_   512    // hidden
#define I_   128    // input size
#define G4   2048   // 4*H
#define SEQ  100
#define DEC  29
#define OUT_ 128
#define TEAM 16     // blocks per row-slab team

typedef __attribute__((ext_vector_type(8))) short bf16x8;
typedef __attribute__((ext_vector_type(4))) float f32x4;
typedef __attribute__((address_space(3))) unsigned int       lds_u32;
typedef __attribute__((address_space(1))) const unsigned int glb_u32c;

__device__ inline unsigned short f2bf(float f) {
    union { float f; unsigned int u; } v; v.f = f;
    unsigned int u = v.u + 0x7fffu + ((v.u >> 16) & 1u);
    return (unsigned short)(u >> 16);
}
__device__ inline float sigm(float x)  { return 1.f / (1.f + __expf(-x)); }
__device__ inline float tanh_(float x) { return 2.f / (1.f + __expf(-2.f * x)) - 1.f; }

// aux: 0 = normal (L1/L2 cached); 17 = SC0|SC1 coherent bypass (read from L3
// coherence point — required for cross-XCD-produced data, leaves L2 intact).
template <int AUX>
__device__ inline void gl16(const unsigned short* g, unsigned short* l) {
    __builtin_amdgcn_global_load_lds((glb_u32c*)g, (lds_u32*)l, 16, 0, AUX);
}

// Persistent encoder+decoder+projection kernel.
// Grid 256 blocks x 512 thr. Block tile: M=128 batch rows x 32 hidden cols
// (x 4 gates). rg = blockIdx&15 (row slab / team id), cg = blockIdx>>4.
// Per-step team sync: monotonic cnt/gen counting barrier, RELAXED agent
// atomics only — NO __threadfence, so L2 contents (W tiles) survive across
// steps. h exchange: sc1 write-through stores + sc1-bypass staging loads.
// LDS 64 KB: double-buffered {A 16KB | B 16KB} chunk pair (k-chunk = 64);
// first 8 KB reused as the h-repack staging area in the epilogue.
__global__ __launch_bounds__(512, 2) void persist(
    const unsigned short* __restrict__ h0b,   // [B_,H_] bf16 initial h
    const unsigned short* __restrict__ xbf,   // [SEQ,B_,I_] bf16 inputs
    const unsigned short* __restrict__ Wce,   // [G4,640] enc weights (Whh|Wih)
    const unsigned short* __restrict__ Wd,    // [G4,512] dec combined weights
    const unsigned short* __restrict__ Wl,    // [OUT_,512] output proj
    const float* __restrict__ be, const float* __restrict__ bd,
    const float* __restrict__ blin,
    const float* __restrict__ c_enc0, const float* __restrict__ c_dec0,
    unsigned short* __restrict__ hp0, unsigned short* __restrict__ hp1,
    unsigned short* __restrict__ hs,          // [30,B_,H_] bf16
    float* __restrict__ out_y,                // [30,B_,OUT_]
    float* __restrict__ out_hEnc, float* __restrict__ out_cEnc,
    float* __restrict__ out_hDec, float* __restrict__ out_cDec,
    unsigned int* __restrict__ bar)           // [16][64] uints (cnt @0, gen @32)
{
    __shared__ unsigned short smem[32768];    // 64 KB

    const int tid  = threadIdx.x;
    const int b    = blockIdx.x;
    const int rg   = b & 15;                  // row-slab / team id
    const int cgB  = b >> 4;                  // col-group 0..15
    const int m0   = rg * 128;
    const int c0   = cgB * 32;

    const int lane = tid & 63, w = tid >> 6;
    const int quad = lane >> 4, l16 = lane & 15;
    const int w_m  = w >> 1, w_n = w & 1;

    unsigned int* bcnt = bar + rg * 64;
    unsigned int* bgen = bcnt + 32;           // 128 B away: separate line
    unsigned int  my_gen = 0;

    // ---- staging geometry (same swizzle as verified round-2 kernel) ----
    const int  segl = (lane & 7) ^ ((lane >> 3) & 7);
    const bool isA  = (w < 4);
    const int  wS   = isA ? w : (w - 4);
    const int  sRow = wS * 32 + (lane >> 3);   // stage row 0..127

    int offA[2][2], offB[4][2];
#pragma unroll
    for (int rf = 0; rf < 2; ++rf)
#pragma unroll
        for (int ks = 0; ks < 2; ++ks) {
            const int row = w_m * 32 + rf * 16 + l16;
            const int seg = ks * 4 + quad;
            offA[rf][ks] = row * 128 + ((seg ^ (row & 7)) * 16);
        }
#pragma unroll
    for (int g = 0; g < 4; ++g)
#pragma unroll
        for (int ks = 0; ks < 2; ++ks) {
            const int row = g * 32 + w_n * 16 + l16;
            const int seg = ks * 4 + quad;
            offB[g][ks] = 16384 + row * 128 + ((seg ^ (row & 7)) * 16);
        }

    f32x4 acc[2][4];
    float c_reg[2][4];
    const int col = c0 + w_n * 16 + l16;

    // stage one 64-k chunk into buffer `buf`; coh => sc1-bypass for the h part
    auto stage = [&](const unsigned short* Asrc, const unsigned short* Xsrc,
                     const unsigned short* Wsrc, int Kw, int gs, int cb,
                     int kc, int buf, bool coh) {
        unsigned short* dst = smem + buf * 16384 + (isA ? 0 : 8192) + wS * 2048;
        if (isA) {
            if (Xsrc && kc >= 8) {   // encoder x-chunks (k 512..639): read-only, cached
                const unsigned short* g0 =
                    Xsrc + (size_t)(m0 + sRow) * I_ + (kc - 8) * 64 + segl * 8;
#pragma unroll
                for (int i = 0; i < 4; ++i)
                    gl16<0>(g0 + (size_t)(i * 8) * I_, dst + i * 512);
            } else {
                const unsigned short* g0 =
                    Asrc + (size_t)(m0 + sRow) * H_ + kc * 64 + segl * 8;
                if (coh) {
#pragma unroll
                    for (int i = 0; i < 4; ++i)
                        gl16<17>(g0 + (size_t)(i * 8) * H_, dst + i * 512);
                } else {
#pragma unroll
                    for (int i = 0; i < 4; ++i)
                        gl16<0>(g0 + (size_t)(i * 8) * H_, dst + i * 512);
                }
            }
        } else {                     // weights: plain, stays hot in L2
#pragma unroll
            for (int i = 0; i < 4; ++i) {
                const int rowN  = sRow + i * 8;
                const int rglob = (rowN >> 5) * gs + cb + (rowN & 31);
                gl16<0>(Wsrc + (size_t)rglob * Kw + kc * 64 + segl * 8, dst + i * 512);
            }
        }
    };

    // full K-loop GEMM for this block's tile, double-buffered
    auto gemm = [&](const unsigned short* Asrc, const unsigned short* Xsrc,
                    const unsigned short* Wsrc, int Kw, int gs, int cb, bool coh) {
#pragma unroll
        for (int rf = 0; rf < 2; ++rf)
#pragma unroll
            for (int g = 0; g < 4; ++g) acc[rf][g] = (f32x4){0.f, 0.f, 0.f, 0.f};
        const int kcN = Kw >> 6;
        stage(Asrc, Xsrc, Wsrc, Kw, gs, cb, 0, 0, coh);
        for (int kc = 0; kc < kcN; ++kc) {
            const int buf = kc & 1;
            __syncthreads();
            if (kc + 1 < kcN)
                stage(Asrc, Xsrc, Wsrc, Kw, gs, cb, kc + 1, buf ^ 1, coh);
            const char* sb = (const char*)smem + buf * 32768;
#pragma unroll
            for (int ks = 0; ks < 2; ++ks) {
                bf16x8 a0 = *(const bf16x8*)(sb + offA[0][ks]);
                bf16x8 a1 = *(const bf16x8*)(sb + offA[1][ks]);
#pragma unroll
                for (int g = 0; g < 4; ++g) {
                    bf16x8 bb = *(const bf16x8*)(sb + offB[g][ks]);
                    acc[0][g] = __builtin_amdgcn_mfma_f32_16x16x32_bf16(a0, bb, acc[0][g], 0, 0, 0);
                    acc[1][g] = __builtin_amdgcn_mfma_f32_16x16x32_bf16(a1, bb, acc[1][g], 0, 0, 0);
                }
            }
        }
        __syncthreads();
    };

    // Monotonic counting barrier (no reset => no reset/gen reorder race).
    // No fences: h data was written through (sc1) and drained (vmcnt0 before
    // s_barrier), so the relaxed RMW at the coherence point is ordered after it.
    auto team_barrier = [&]() {
        __syncthreads();
        if (tid == 0) {
            unsigned old = __hip_atomic_fetch_add(bcnt, 1u, __ATOMIC_RELAXED,
                                                  __HIP_MEMORY_SCOPE_AGENT);
            if (old == (my_gen + 1u) * TEAM - 1u) {
                __hip_atomic_fetch_add(bgen, 1u, __ATOMIC_RELAXED,
                                       __HIP_MEMORY_SCOPE_AGENT);
            } else {
                while (__hip_atomic_load(bgen, __ATOMIC_RELAXED,
                                         __HIP_MEMORY_SCOPE_AGENT) <= my_gen)
                    __builtin_amdgcn_s_sleep(2);
            }
        }
        my_gen++;
        __syncthreads();
    };

    // LSTM cell epilogue: compute c/h, repack h via LDS, write through (sc1).
    auto cell_epi = [&](float b0, float b1, float b2, float b3,
                        unsigned short* dst, float* hdump, float* cdump) {
        unsigned short* hstage = smem;      // reuse buf0-A region (post-gemm)
#pragma unroll
        for (int rf = 0; rf < 2; ++rf)
#pragma unroll
            for (int j = 0; j < 4; ++j) {
                const int row_l = w_m * 32 + rf * 16 + quad * 4 + j;
                const float gi = acc[rf][0][j] + b0;
                const float gf = acc[rf][1][j] + b1;
                const float gg = acc[rf][2][j] + b2;
                const float go = acc[rf][3][j] + b3;
                const float ii = sigm(gi), ff = sigm(gf);
                const float g2 = tanh_(gg), oo = sigm(go);
                const float cn = ff * c_reg[rf][j] + ii * g2;
                c_reg[rf][j] = cn;
                const float hn = oo * tanh_(cn);
                hstage[row_l * 32 + (w_n * 16 + l16)] = f2bf(hn);
                if (hdump) {
                    const size_t idx = (size_t)(m0 + row_l) * H_ + col;
                    hdump[idx] = hn; cdump[idx] = cn;
                }
            }
        __syncthreads();
        const unsigned int* h32 = (const unsigned int*)smem;
#pragma unroll
        for (int i = 0; i < 4; ++i) {
            const int idx = tid + i * 512;          // 0..2047
            const int row = idx >> 4, cp = idx & 15;
            unsigned int* gp =
                (unsigned int*)(dst + (size_t)(m0 + row) * H_ + c0) + cp;
            __hip_atomic_store(gp, h32[idx], __ATOMIC_RELAXED,
                               __HIP_MEMORY_SCOPE_AGENT);
        }
    };

    // ================= encoder: 100 steps =================
    {
        const float b0 = be[col], b1 = be[H_ + col],
                    b2 = be[2 * H_ + col], b3 = be[3 * H_ + col];
#pragma unroll
        for (int rf = 0; rf < 2; ++rf)
#pragma unroll
            for (int j = 0; j < 4; ++j) {
                const int row = m0 + w_m * 32 + rf * 16 + quad * 4 + j;
                c_reg[rf][j] = c_enc0[(size_t)row * H_ + col];
            }
        for (int t = 0; t < SEQ; ++t) {
            const unsigned short* src = (t == 0) ? h0b : ((t & 1) ? hp0 : hp1);
            unsigned short*       dst = (t == SEQ - 1) ? hs : ((t & 1) ? hp1 : hp0);
            const bool last = (t == SEQ - 1);
            gemm(src, xbf + (size_t)t * B_ * I_, Wce, 640, H_, c0, true);
            cell_epi(b0, b1, b2, b3, dst,
                     last ? out_hEnc : nullptr, last ? out_cEnc : nullptr);
            team_barrier();
        }
    }

    // ================= decoder: 29 steps =================
    {
        const float b0 = bd[col], b1 = bd[H_ + col],
                    b2 = bd[2 * H_ + col], b3 = bd[3 * H_ + col];
#pragma unroll
        for (int rf = 0; rf < 2; ++rf)
#pragma unroll
            for (int j = 0; j < 4; ++j) {
                const int row = m0 + w_m * 32 + rf * 16 + quad * 4 + j;
                c_reg[rf][j] = c_dec0[(size_t)row * H_ + col];
            }
        for (int s = 0; s < DEC; ++s) {
            const bool last = (s == DEC - 1);
            gemm(hs + (size_t)s * B_ * H_, nullptr, Wd, 512, H_, c0, true);
            cell_epi(b0, b1, b2, b3, hs + (size_t)(s + 1) * B_ * H_,
                     last ? out_hDec : nullptr, last ? out_cDec : nullptr);
            team_barrier();
        }
    }

    // ===== output projection: y[s] = hs[s] @ Wl^T + blin (team-local rows) ===
    for (int s = cgB; s < DEC + 1; s += 16) {
        gemm(hs + (size_t)s * B_ * H_, nullptr, Wl, 512, 32, 0, true);
#pragma unroll
        for (int g = 0; g < 4; ++g) {
            const int ocol = g * 32 + w_n * 16 + l16;
            const float bb = blin[ocol];
#pragma unroll
            for (int rf = 0; rf < 2; ++rf)
#pragma unroll
                for (int j = 0; j < 4; ++j) {
                    const int row = m0 + w_m * 32 + rf * 16 + quad * 4 + j;
                    out_y[(size_t)s * B_ * OUT_ + (size_t)row * OUT_ + ocol] =
                        acc[rf][g][j] + bb;
                }
        }
    }
}

// Weight prep: Wce[r][k] = k<512 ? Whh_e[r][k] : Wih_e[r][k-512];
// Wd = bf16(Wih_d + Whh_d); Wl = bf16(W_lin); biases combined.
__global__ void prep(const float* __restrict__ whh_e, const float* __restrict__ wih_e,
                     const float* __restrict__ wih_d, const float* __restrict__ whh_d,
                     const float* __restrict__ wlin,
                     const float* __restrict__ bie, const float* __restrict__ bhe,
                     const float* __restrict__ bid, const float* __restrict__ bhd,
                     unsigned short* __restrict__ Wce, unsigned short* __restrict__ Wd,
                     unsigned short* __restrict__ Wl,
                     float* __restrict__ be, float* __restrict__ bd)
{
    const int i = blockIdx.x * blockDim.x + threadIdx.x;
    if (i < G4 * 640) {
        const int r = i / 640, k = i % 640;
        Wce[i] = f2bf(k < H_ ? whh_e[r * H_ + k] : wih_e[r * I_ + (k - H_)]);
    }
    if (i < G4 * H_)   Wd[i] = f2bf(wih_d[i] + whh_d[i]);
    if (i < OUT_ * H_) Wl[i] = f2bf(wlin[i]);
    if (i < G4) { be[i] = bie[i] + bhe[i]; bd[i] = bid[i] + bhd[i]; }
}

__global__ void xconv(const float* __restrict__ x, unsigned short* __restrict__ xb, int n4)
{
    const int i = blockIdx.x * blockDim.x + threadIdx.x;
    if (i < n4) {
        const float4 f = *(const float4*)(x + (size_t)i * 4);
        ushort4 o;
        o.x = f2bf(f.x); o.y = f2bf(f.y); o.z = f2bf(f.z); o.w = f2bf(f.w);
        *(ushort4*)(xb + (size_t)i * 4) = o;
    }
}

__global__ void inith(const float* __restrict__ h0, unsigned short* __restrict__ hb)
{
    const int i = blockIdx.x * blockDim.x + threadIdx.x;
    if (i < B_ * H_) hb[i] = f2bf(h0[i]);
}

extern "C" void kernel_launch(void* const* d_in, const int* in_sizes, int n_in,
                              void* d_out, int out_size, void* d_ws, size_t ws_size,
                              hipStream_t stream) {
    (void)in_sizes; (void)n_in; (void)out_size; (void)ws_size;
    const float* input  = (const float*)d_in[0];
    const float* h_enc0 = (const float*)d_in[1];
    // d_in[2] hidden_decoder is unused by the reference
    const float* c_enc0 = (const float*)d_in[3];
    const float* c_dec0 = (const float*)d_in[4];
    const float* Wih_e  = (const float*)d_in[5];
    const float* Whh_e  = (const float*)d_in[6];
    const float* bih_e  = (const float*)d_in[7];
    const float* bhh_e  = (const float*)d_in[8];
    const float* Wih_d  = (const float*)d_in[9];
    const float* Whh_d  = (const float*)d_in[10];
    const float* bih_d  = (const float*)d_in[11];
    const float* bhh_d  = (const float*)d_in[12];
    const float* Wlin   = (const float*)d_in[13];
    const float* blin   = (const float*)d_in[14];
    float* out = (float*)d_out;

    char* ws = (char*)d_ws;
    size_t off = 0;
    auto alloc = [&](size_t bytes) -> void* {
        void* p = ws + off;
        off = (off + bytes + 255) & ~(size_t)255;
        return p;
    };
    unsigned short* Wce = (unsigned short*)alloc((size_t)G4 * 640 * 2);
    unsigned short* Wd  = (unsigned short*)alloc((size_t)G4 * H_ * 2);
    unsigned short* Wl  = (unsigned short*)alloc((size_t)OUT_ * H_ * 2);
    float* be = (float*)alloc((size_t)G4 * 4);
    float* bd = (float*)alloc((size_t)G4 * 4);
    unsigned short* h0b = (unsigned short*)alloc((size_t)B_ * H_ * 2);
    unsigned short* hp0 = (unsigned short*)alloc((size_t)B_ * H_ * 2);
    unsigned short* hp1 = (unsigned short*)alloc((size_t)B_ * H_ * 2);
    unsigned short* xbf = (unsigned short*)alloc((size_t)SEQ * B_ * I_ * 2);
    unsigned short* hs  = (unsigned short*)alloc((size_t)(DEC + 1) * B_ * H_ * 2);
    unsigned int*   bar = (unsigned int*)alloc(16 * 64 * 4);

    float* out_y    = out;                                   // [30, B_, OUT_]
    float* out_hEnc = out + (size_t)(DEC + 1) * B_ * OUT_;
    float* out_hDec = out_hEnc + (size_t)B_ * H_;
    float* out_cEnc = out_hDec + (size_t)B_ * H_;
    float* out_cDec = out_cEnc + (size_t)B_ * H_;

    prep<<<(G4 * 640 + 255) / 256, 256, 0, stream>>>(
        Whh_e, Wih_e, Wih_d, Whh_d, Wlin, bih_e, bhh_e, bih_d, bhh_d,
        Wce, Wd, Wl, be, bd);
    xconv<<<(SEQ * B_ * I_ / 4 + 255) / 256, 256, 0, stream>>>(input, xbf, SEQ * B_ * I_ / 4);
    inith<<<(B_ * H_ + 255) / 256, 256, 0, stream>>>(h_enc0, h0b);
    hipMemsetAsync(bar, 0, 16 * 64 * 4, stream);

    persist<<<256, 512, 0, stream>>>(
        h0b, xbf, Wce, Wd, Wl, be, bd, blin, c_enc0, c_dec0,
        hp0, hp1, hs, out_y, out_hEnc, out_cEnc, out_hDec, out_cDec, bar);
}